// Round 3
// baseline (328.743 us; speedup 1.0000x reference)
//
#include <hip/hip_runtime.h>

namespace {

constexpr int B = 4, L = 2048, H = 8, E = 64;
constexpr int RS = H * E;           // 512 floats: row stride in [B,L,H,E]
constexpr float SCALE = 0.125f;     // 1/sqrt(64)

typedef __attribute__((ext_vector_type(8))) short bf16x8;
typedef __attribute__((ext_vector_type(4))) float f32x4;

__device__ inline short f2bf(float f) {
  union { float f; unsigned u; } c; c.f = f;
  unsigned r = (c.u + 0x7FFFu + ((c.u >> 16) & 1u)) >> 16;   // RNE
  return (short)r;
}

__device__ inline bf16x8 pack8(float4 a, float4 b) {
  bf16x8 r;
  r[0] = f2bf(a.x); r[1] = f2bf(a.y); r[2] = f2bf(a.z); r[3] = f2bf(a.w);
  r[4] = f2bf(b.x); r[5] = f2bf(b.y); r[6] = f2bf(b.z); r[7] = f2bf(b.w);
  return r;
}

// One TASK = 16 q-rows of one (b,h). Each task is split across a PAIR of
// waves (key-range halves) merged via LDS online-softmax merge. Swapped
// S^T = K·Q^T keeps the softmax row lane-local; P feeds PV's A-operand
// in place.
__global__ __launch_bounds__(256, 8)
void fa_mfma(const float* __restrict__ Q, const float* __restrict__ K,
             const float* __restrict__ V, float* __restrict__ O)
{
  const int lane = threadIdx.x & 63;
  const int wv   = threadIdx.x >> 6;
  const int pairIdx = wv >> 1;                       // 0,1 within block
  const int half    = wv & 1;                        // 0 = front half keys
  const int P    = (int)blockIdx.x * 2 + pairIdx;    // 0..4095
  const int task = 4095 - P;                         // longest tasks first
  const int bh   = task & 31;
  const int q16  = task >> 5;
  const int b = bh >> 3, h = bh & 7;

  const int ln = lane & 15;                          // row/col within 16-tile
  const int lg = lane >> 4;                          // lane group 0..3
  const int d0 = lg * 4;

  const size_t base = (size_t)b * L * RS + (size_t)h * E;
  const float* Qb = Q + base;
  const float* Kb = K + base;
  const float* Vb = V + base;
  float*       Ob = O + base;

  const int qrow0 = q16 * 16;

  // Q fragments (B-operand: col = q-row qrow0+ln; k-dims d0.. pattern)
  const float* qp = Qb + (size_t)(qrow0 + ln) * RS;
  const bf16x8 qf0 = pack8(*(const float4*)(qp + d0),      *(const float4*)(qp + d0 + 16));
  const bf16x8 qf1 = pack8(*(const float4*)(qp + d0 + 32), *(const float4*)(qp + d0 + 48));

  f32x4 acc[4];                     // [nt]: dim = ln+16*nt, q-row = d0+r
#pragma unroll
  for (int nt = 0; nt < 4; ++nt) acc[nt] = (f32x4){0.f, 0.f, 0.f, 0.f};
  float m = -1e30f, lsum = 0.f;

  const int qmax   = qrow0 + 15;
  const int ns     = (qmax >> 5) + 1;                // total 32-key steps
  const int hs     = ns >> 1;
  const int stepLo = half ? hs : 0;
  const int stepHi = half ? ns : hs;

  for (int step = stepLo; step < stepHi; ++step) {
    const int kv0 = step * 32;

    // ---- K fragments (A-operand: row = key; two 16-key blocks) ----
    const float* kp0 = Kb + (size_t)(kv0 + ln) * RS;
    const float* kp1 = kp0 + (size_t)16 * RS;
    const bf16x8 kf00 = pack8(*(const float4*)(kp0 + d0),      *(const float4*)(kp0 + d0 + 16));
    const bf16x8 kf01 = pack8(*(const float4*)(kp0 + d0 + 32), *(const float4*)(kp0 + d0 + 48));
    const bf16x8 kf10 = pack8(*(const float4*)(kp1 + d0),      *(const float4*)(kp1 + d0 + 16));
    const bf16x8 kf11 = pack8(*(const float4*)(kp1 + d0 + 32), *(const float4*)(kp1 + d0 + 48));

    f32x4 st0 = (f32x4){0.f,0.f,0.f,0.f}, st1 = st0;
    st0 = __builtin_amdgcn_mfma_f32_16x16x32_bf16(kf00, qf0, st0, 0, 0, 0);
    st0 = __builtin_amdgcn_mfma_f32_16x16x32_bf16(kf01, qf1, st0, 0, 0, 0);
    st1 = __builtin_amdgcn_mfma_f32_16x16x32_bf16(kf10, qf0, st1, 0, 0, 0);
    st1 = __builtin_amdgcn_mfma_f32_16x16x32_bf16(kf11, qf1, st1, 0, 0, 0);

    // ---- per-lane scores: 8 keys of its q-row (qrow0+ln) ----
    float x[8];
#pragma unroll
    for (int r = 0; r < 4; ++r) { x[r] = SCALE * st0[r]; x[4 + r] = SCALE * st1[r]; }

    if (step == ns - 1) {           // only the global last step crosses diag
      const int qr = qrow0 + ln;
#pragma unroll
      for (int e = 0; e < 8; ++e) {
        const int key = kv0 + ((e >> 2) << 4) + d0 + (e & 3);
        if (key > qr) x[e] = -1e30f;
      }
    }

    // ---- online softmax (state replicated across the 4-lane group) ----
    float mx = x[0];
#pragma unroll
    for (int e = 1; e < 8; ++e) mx = fmaxf(mx, x[e]);
    mx = fmaxf(mx, __shfl_xor(mx, 16, 64));
    mx = fmaxf(mx, __shfl_xor(mx, 32, 64));
    const float newm = fmaxf(m, mx);
    const float sc = __expf(m - newm);
    float p[8]; float ps = 0.f;
#pragma unroll
    for (int e = 0; e < 8; ++e) { p[e] = __expf(x[e] - newm); ps += p[e]; }
    ps += __shfl_xor(ps, 16, 64);
    ps += __shfl_xor(ps, 32, 64);
    lsum = lsum * sc + ps;
    m = newm;

    // rescale factors for the rows this lane accumulates (rows d0+r)
    float scr[4];
#pragma unroll
    for (int r = 0; r < 4; ++r) scr[r] = __shfl(sc, d0 + r, 64);
#pragma unroll
    for (int nt = 0; nt < 4; ++nt) {
      acc[nt][0] *= scr[0]; acc[nt][1] *= scr[1];
      acc[nt][2] *= scr[2]; acc[nt][3] *= scr[3];
    }

    // ---- P fragment (in place: e = key slot, matches A-layout) ----
    bf16x8 pf;
#pragma unroll
    for (int e = 0; e < 8; ++e) pf[e] = f2bf(p[e]);

    // ---- V fragments (B-operand: col = dim ln+16nt, k = key) + PV ----
    const float* vp0 = Vb + (size_t)kv0 * RS + ln;
#pragma unroll
    for (int nt = 0; nt < 4; ++nt) {
      const float* vp = vp0 + 16 * nt;
      bf16x8 vf;
#pragma unroll
      for (int e = 0; e < 8; ++e) {
        const int key = ((e >> 2) << 4) + d0 + (e & 3);
        vf[e] = f2bf(vp[(size_t)key * RS]);
      }
      acc[nt] = __builtin_amdgcn_mfma_f32_16x16x32_bf16(pf, vf, acc[nt], 0, 0, 0);
    }
  }

  // ---- pair merge: wave0 of the pair publishes acc/m/l; wave1 merges ----
  __shared__ float accS[2][16][64];
  __shared__ float mS[2][2][16];     // [pair][half][row]
  __shared__ float lS[2][2][16];

  if (half == 0) {
#pragma unroll
    for (int nt = 0; nt < 4; ++nt)
#pragma unroll
      for (int r = 0; r < 4; ++r)
        accS[pairIdx][d0 + r][ln + 16 * nt] = acc[nt][r];
  }
  if (lane < 16) {
    mS[pairIdx][half][ln] = m;
    lS[pairIdx][half][ln] = lsum;
  }
  __syncthreads();

  if (half == 1) {
    float s0[4], s1[4], inv[4];
#pragma unroll
    for (int r = 0; r < 4; ++r) {
      const int row = d0 + r;
      const float m0 = mS[pairIdx][0][row];
      const float m1 = mS[pairIdx][1][row];
      const float mm = fmaxf(m0, m1);
      const float e0 = __expf(m0 - mm);
      const float e1 = __expf(m1 - mm);
      const float ll = lS[pairIdx][0][row] * e0 + lS[pairIdx][1][row] * e1;
      s0[r] = e0; s1[r] = e1; inv[r] = 1.0f / ll;
    }
#pragma unroll
    for (int nt = 0; nt < 4; ++nt) {
#pragma unroll
      for (int r = 0; r < 4; ++r) {
        const float v = (accS[pairIdx][d0 + r][ln + 16 * nt] * s0[r] +
                         acc[nt][r] * s1[r]) * inv[r];
        Ob[(size_t)(qrow0 + d0 + r) * RS + (ln + 16 * nt)] = v;
      }
    }
  }
}

} // namespace

extern "C" void kernel_launch(void* const* d_in, const int* in_sizes, int n_in,
                              void* d_out, int out_size, void* d_ws, size_t ws_size,
                              hipStream_t stream) {
  const float* Q = (const float*)d_in[0];
  const float* K = (const float*)d_in[1];
  const float* V = (const float*)d_in[2];
  float* O = (float*)d_out;
  (void)in_sizes; (void)n_in; (void)out_size; (void)d_ws; (void)ws_size;

  const int tasks = (L / 16) * B * H;     // 4096 tasks, 2 waves each
  fa_mfma<<<tasks / 2, 256, 0, stream>>>(Q, K, V, O);
}

// Round 4
// 156.995 us; speedup vs baseline: 2.0940x; 2.0940x over previous
//
#include <hip/hip_runtime.h>
#include <hip/hip_bf16.h>

namespace {

constexpr int B = 4, L = 2048, H = 8, E = 64;
constexpr int RS = H * E;           // 512 floats: row stride in [B,L,H,E]
constexpr float SCALE = 0.125f;     // 1/sqrt(64)

typedef __attribute__((ext_vector_type(8))) short bf16x8;
typedef __attribute__((ext_vector_type(4))) float f32x4;

__device__ inline unsigned cvt2(float a, float b) {
  __hip_bfloat162 h = __float22bfloat162_rn(make_float2(a, b));  // v_cvt_pk_bf16_f32
  union { __hip_bfloat162 h; unsigned u; } c; c.h = h; return c.u;
}

__device__ inline bf16x8 pack8(float4 a, float4 b) {
  union { bf16x8 v; unsigned u[4]; } r;
  r.u[0] = cvt2(a.x, a.y); r.u[1] = cvt2(a.z, a.w);
  r.u[2] = cvt2(b.x, b.y); r.u[3] = cvt2(b.z, b.w);
  return r.v;
}

// One TASK = 16 q-rows of one (b,h), split across a PAIR of waves
// (front/back key halves), merged via LDS online-softmax merge.
// Swapped S^T = K·Q^T keeps the softmax row lane-local; P feeds PV's
// A-operand in place.
__global__ __launch_bounds__(256)
void fa_mfma(const float* __restrict__ Q, const float* __restrict__ K,
             const float* __restrict__ V, float* __restrict__ O)
{
  const int lane = threadIdx.x & 63;
  const int wv   = threadIdx.x >> 6;
  const int pairIdx = wv >> 1;                       // 0,1 within block
  const int half    = wv & 1;                        // 0 = front half keys
  const int P    = (int)blockIdx.x * 2 + pairIdx;    // 0..4095
  const int task = 4095 - P;                         // longest tasks first
  const int bh   = task & 31;
  const int q16  = task >> 5;
  const int b = bh >> 3, h = bh & 7;

  const int ln = lane & 15;                          // row/col within 16-tile
  const int lg = lane >> 4;                          // lane group 0..3
  const int d0 = lg * 4;

  const size_t base = (size_t)b * L * RS + (size_t)h * E;
  const float* Qb = Q + base;
  const float* Kb = K + base;
  const float* Vb = V + base;
  float*       Ob = O + base;

  const int qrow0 = q16 * 16;

  // Q fragments (B-operand: col = q-row qrow0+ln; k-dims d0.. pattern)
  const float* qp = Qb + (size_t)(qrow0 + ln) * RS;
  const bf16x8 qf0 = pack8(*(const float4*)(qp + d0),      *(const float4*)(qp + d0 + 16));
  const bf16x8 qf1 = pack8(*(const float4*)(qp + d0 + 32), *(const float4*)(qp + d0 + 48));

  f32x4 acc[4];                     // [nt]: dim = ln+16*nt, q-row = d0+r
#pragma unroll
  for (int nt = 0; nt < 4; ++nt) acc[nt] = (f32x4){0.f, 0.f, 0.f, 0.f};
  float m = -1e30f, lsum = 0.f;

  const int qmax   = qrow0 + 15;
  const int ns     = (qmax >> 5) + 1;                // total 32-key steps
  const int hs     = ns >> 1;
  const int stepLo = half ? hs : 0;
  const int stepHi = half ? ns : hs;

  for (int step = stepLo; step < stepHi; ++step) {
    const int kv0 = step * 32;

    // ---- K fragments (A-operand: row = key; two 16-key blocks) ----
    const float* kp0 = Kb + (size_t)(kv0 + ln) * RS;
    const float* kp1 = kp0 + (size_t)16 * RS;
    const bf16x8 kf00 = pack8(*(const float4*)(kp0 + d0),      *(const float4*)(kp0 + d0 + 16));
    const bf16x8 kf01 = pack8(*(const float4*)(kp0 + d0 + 32), *(const float4*)(kp0 + d0 + 48));
    const bf16x8 kf10 = pack8(*(const float4*)(kp1 + d0),      *(const float4*)(kp1 + d0 + 16));
    const bf16x8 kf11 = pack8(*(const float4*)(kp1 + d0 + 32), *(const float4*)(kp1 + d0 + 48));

    f32x4 st0 = (f32x4){0.f,0.f,0.f,0.f}, st1 = st0;
    st0 = __builtin_amdgcn_mfma_f32_16x16x32_bf16(kf00, qf0, st0, 0, 0, 0);
    st0 = __builtin_amdgcn_mfma_f32_16x16x32_bf16(kf01, qf1, st0, 0, 0, 0);
    st1 = __builtin_amdgcn_mfma_f32_16x16x32_bf16(kf10, qf0, st1, 0, 0, 0);
    st1 = __builtin_amdgcn_mfma_f32_16x16x32_bf16(kf11, qf1, st1, 0, 0, 0);

    // ---- per-lane scores: 8 keys of its q-row (qrow0+ln) ----
    float x[8];
#pragma unroll
    for (int r = 0; r < 4; ++r) { x[r] = SCALE * st0[r]; x[4 + r] = SCALE * st1[r]; }

    if (step == ns - 1) {           // only the global last step crosses diag
      const int qr = qrow0 + ln;
#pragma unroll
      for (int e = 0; e < 8; ++e) {
        const int key = kv0 + ((e >> 2) << 4) + d0 + (e & 3);
        if (key > qr) x[e] = -1e30f;
      }
    }

    // ---- online softmax (state replicated across the 4-lane group) ----
    float mx = x[0];
#pragma unroll
    for (int e = 1; e < 8; ++e) mx = fmaxf(mx, x[e]);
    mx = fmaxf(mx, __shfl_xor(mx, 16, 64));
    mx = fmaxf(mx, __shfl_xor(mx, 32, 64));
    const float newm = fmaxf(m, mx);
    const float sc = __expf(m - newm);
    float p[8]; float ps = 0.f;
#pragma unroll
    for (int e = 0; e < 8; ++e) { p[e] = __expf(x[e] - newm); ps += p[e]; }
    ps += __shfl_xor(ps, 16, 64);
    ps += __shfl_xor(ps, 32, 64);
    lsum = lsum * sc + ps;
    m = newm;

    // rescale factors for the rows this lane accumulates (rows d0+r)
    float scr[4];
#pragma unroll
    for (int r = 0; r < 4; ++r) scr[r] = __shfl(sc, d0 + r, 64);
#pragma unroll
    for (int nt = 0; nt < 4; ++nt) {
      acc[nt][0] *= scr[0]; acc[nt][1] *= scr[1];
      acc[nt][2] *= scr[2]; acc[nt][3] *= scr[3];
    }

    // ---- P fragment (in place: e = key slot, matches A-layout) ----
    union { bf16x8 v; unsigned u[4]; } pf;
#pragma unroll
    for (int e = 0; e < 4; ++e) pf.u[e] = cvt2(p[2*e], p[2*e+1]);

    // ---- V fragments (B-operand: col = dim ln+16nt, k = key) + PV ----
    const float* vp0 = Vb + (size_t)kv0 * RS + ln;
#pragma unroll
    for (int nt = 0; nt < 4; ++nt) {
      const float* vp = vp0 + 16 * nt;
      union { bf16x8 v; unsigned u[4]; } vf;
#pragma unroll
      for (int e = 0; e < 4; ++e) {
        const int k0 = ((2*e) >> 2 << 4) + d0 + ((2*e) & 3);
        const int k1 = (((2*e+1)) >> 2 << 4) + d0 + ((2*e+1) & 3);
        vf.u[e] = cvt2(vp[(size_t)k0 * RS], vp[(size_t)k1 * RS]);
      }
      acc[nt] = __builtin_amdgcn_mfma_f32_16x16x32_bf16(pf.v, vf.v, acc[nt], 0, 0, 0);
    }
  }

  // ---- pair merge: wave0 of the pair publishes acc/m/l; wave1 merges ----
  __shared__ float accS[2][16][68];   // stride 68: 4-way -> 2-way (free)
  __shared__ float mS[2][2][16];      // [pair][half][row]
  __shared__ float lS[2][2][16];

  if (half == 0) {
#pragma unroll
    for (int nt = 0; nt < 4; ++nt)
#pragma unroll
      for (int r = 0; r < 4; ++r)
        accS[pairIdx][d0 + r][ln + 16 * nt] = acc[nt][r];
  }
  if (lane < 16) {
    mS[pairIdx][half][ln] = m;
    lS[pairIdx][half][ln] = lsum;
  }
  __syncthreads();

  if (half == 1) {
    float s0[4], s1[4], inv[4];
#pragma unroll
    for (int r = 0; r < 4; ++r) {
      const int row = d0 + r;
      const float m0 = mS[pairIdx][0][row];
      const float m1 = mS[pairIdx][1][row];
      const float mm = fmaxf(m0, m1);
      const float e0 = __expf(m0 - mm);
      const float e1 = __expf(m1 - mm);
      const float ll = lS[pairIdx][0][row] * e0 + lS[pairIdx][1][row] * e1;
      s0[r] = e0; s1[r] = e1; inv[r] = 1.0f / ll;
    }
#pragma unroll
    for (int nt = 0; nt < 4; ++nt) {
#pragma unroll
      for (int r = 0; r < 4; ++r) {
        const float v = (accS[pairIdx][d0 + r][ln + 16 * nt] * s0[r] +
                         acc[nt][r] * s1[r]) * inv[r];
        Ob[(size_t)(qrow0 + d0 + r) * RS + (ln + 16 * nt)] = v;
      }
    }
  }
}

} // namespace

extern "C" void kernel_launch(void* const* d_in, const int* in_sizes, int n_in,
                              void* d_out, int out_size, void* d_ws, size_t ws_size,
                              hipStream_t stream) {
  const float* Q = (const float*)d_in[0];
  const float* K = (const float*)d_in[1];
  const float* V = (const float*)d_in[2];
  float* O = (float*)d_out;
  (void)in_sizes; (void)n_in; (void)out_size; (void)d_ws; (void)ws_size;

  const int tasks = (L / 16) * B * H;     // 4096 tasks, 2 waves each
  fa_mfma<<<tasks / 2, 256, 0, stream>>>(Q, K, V, O);
}